// Round 19
// baseline (204.875 us; speedup 1.0000x reference)
//
#include <hip/hip_runtime.h>

#define DEV __device__ __forceinline__

typedef __bf16 bf16x8 __attribute__((ext_vector_type(8)));
typedef float f32x4 __attribute__((ext_vector_type(4)));
typedef float f32x2 __attribute__((ext_vector_type(2)));

constexpr int TOK = 32768;   // B*N tokens
constexpr int D   = 512;
constexpr int P   = 720;
constexpr float EPS = 1e-5f;

DEV unsigned short f2bf(float f) {
  unsigned u = __float_as_uint(f);
  u += 0x7FFFu + ((u >> 16) & 1u);   // RNE (normals; inputs are finite randoms)
  return (unsigned short)(u >> 16);
}

DEV void g2lds16(const void* g, void* l) {
  __builtin_amdgcn_global_load_lds(
      (__attribute__((address_space(1))) void*)g,
      (__attribute__((address_space(3))) void*)l, 16, 0, 0);
}

// ---------------- W_exp [2][D][P] fp32 -> WT [2][P][D] bf16 -----------------
__global__ void wconv_kernel(const float* __restrict__ W,
                             unsigned short* __restrict__ WT) {
  __shared__ float ls[16][17];
  const int e  = blockIdx.z;
  const int d0 = blockIdx.x * 16, p0 = blockIdx.y * 16;
  const int tx = threadIdx.x, ty = threadIdx.y;
  ls[ty][tx] = W[((size_t)e * D + d0 + ty) * P + p0 + tx];
  __syncthreads();
  WT[((size_t)e * P + p0 + ty) * D + d0 + tx] = f2bf(ls[tx][ty]);
}

// ---------------- classifier v15: scalar-operand layer-1 --------------------
// lane = token (64/wave covers TM=64), wave = uniform 32-col slice. W1 rows
// load via readfirstlane-uniform pointers -> s_load (scalar cache, no LDS, no
// vmcnt). x: 1 conflict-free ds_read_b32 per kk. No ws[] staging at all.
// Inner: 32 v_fmac(acc, s_w, v_x) per kk. xs staging + fused xb = r8 verbatim.
__global__ __launch_bounds__(256, 3) void classifier_kernel(
    const float* __restrict__ x,
    const float* __restrict__ W1, const float* __restrict__ b1,
    const float* __restrict__ g1, const float* __restrict__ be1,
    const float* __restrict__ m1, const float* __restrict__ v1,
    const float* __restrict__ W2, const float* __restrict__ b2,
    const float* __restrict__ g2, const float* __restrict__ be2,
    const float* __restrict__ m2, const float* __restrict__ v2,
    const float* __restrict__ W3, const float* __restrict__ b3,
    unsigned short* __restrict__ xb, unsigned long long* __restrict__ masks)
{
  constexpr int TM = 64, BK = 32;
  // pass1: xs[2][32][68] @0 (17408 B); pass2: h1s[128][68] @0, h2s @34816
  __shared__ __align__(16) char smem[43520];
  float (*xs)[32][68] = (float(*)[32][68])smem;
  float (*h1s)[68]    = (float(*)[68])smem;
  float (*h2s)[68]    = (float(*)[68])(smem + 34816);

  const int tid  = threadIdx.x;
  const int lane = tid & 63;
  const int t0   = blockIdx.x * TM;

  // wave-uniform column slice (readfirstlane -> provably uniform -> s_load)
  const int wv = __builtin_amdgcn_readfirstlane(tid >> 6);
  const int c0 = wv * 32;

  // staging maps (r8 verbatim)
  const int xr = tid >> 2;
  const int xc = (tid & 3) * 4;

  const int tt = lane;              // this thread's token

  float acc[32];
  #pragma unroll
  for (int j = 0; j < 32; ++j) acc[j] = 0.f;

  float4 px0, px1;

  auto issue_x = [&](int kt) {
    const float* base = &x[(size_t)(t0 + xr) * D + kt * BK + xc];
    px0 = *reinterpret_cast<const float4*>(base);
    px1 = *reinterpret_cast<const float4*>(base + 16);
  };
  auto commit_x = [&](int b, int kt) {
    xs[b][xc + 0][xr] = px0.x;  xs[b][xc + 1][xr] = px0.y;
    xs[b][xc + 2][xr] = px0.z;  xs[b][xc + 3][xr] = px0.w;
    xs[b][xc + 16][xr] = px1.x; xs[b][xc + 17][xr] = px1.y;
    xs[b][xc + 18][xr] = px1.z; xs[b][xc + 19][xr] = px1.w;
    ushort4 u0, u1;
    u0.x = f2bf(px0.x); u0.y = f2bf(px0.y); u0.z = f2bf(px0.z); u0.w = f2bf(px0.w);
    u1.x = f2bf(px1.x); u1.y = f2bf(px1.y); u1.z = f2bf(px1.z); u1.w = f2bf(px1.w);
    unsigned short* xbase = &xb[(size_t)(t0 + xr) * D + kt * BK + xc];
    *reinterpret_cast<ushort4*>(xbase)      = u0;
    *reinterpret_cast<ushort4*>(xbase + 16) = u1;
  };

  issue_x(0);
  commit_x(0, 0);
  __syncthreads();   // xs[0] ready

  int buf = 0;
  for (int kt = 0; kt < D / BK; ++kt) {
    const int nb = buf ^ 1;
    if (kt < D / BK - 1) issue_x(kt + 1);   // loads in flight across compute
    const float* wtile = W1 + (size_t)(kt * BK) * 128 + c0;   // uniform
    #pragma unroll 4
    for (int kk = 0; kk < BK; ++kk) {
      const float xv = xs[buf][kk][tt];          // 1 ds_read_b32, conflict-free
      const float* wrow = wtile + (size_t)kk * 128;   // uniform -> s_load x2
      #pragma unroll
      for (int j = 0; j < 32; ++j)
        acc[j] = fmaf(wrow[j], xv, acc[j]);      // v_fmac acc, s_w, v_x
    }
    if (kt < D / BK - 1) commit_x(nb, kt + 1);
    __syncthreads();
    buf = nb;
  }

  // BN1 + ReLU -> h1s[col][tok]  (col wave-uniform -> scalar params)
  #pragma unroll 4
  for (int j = 0; j < 32; ++j) {
    const int col = c0 + j;
    const float A  = g1[col] / sqrtf(v1[col] + EPS);
    const float Bc = (b1[col] - m1[col]) * A + be1[col];
    h1s[col][tt] = fmaxf(0.f, fmaf(acc[j], A, Bc));
  }
  __syncthreads();

  // layer 2: per thread 2 tokens x 4 cols (r8 verbatim)
  {
    const int c2 = (tid & 7) * 4;
    const int t2 = (tid >> 3) * 2;
    f32x2 a2[4];
    #pragma unroll
    for (int c = 0; c < 4; ++c) a2[c] = (f32x2)0.f;
    #pragma unroll 8
    for (int j = 0; j < 128; ++j) {
      const f32x2 h = *reinterpret_cast<const f32x2*>(&h1s[j][t2]);
      const float4 w = *reinterpret_cast<const float4*>(&W2[j * 32 + c2]);
      const float wr[4] = {w.x, w.y, w.z, w.w};
      #pragma unroll
      for (int c = 0; c < 4; ++c) {
        f32x2 wv2 = {wr[c], wr[c]};
        a2[c] = __builtin_elementwise_fma(h, wv2, a2[c]);
      }
    }
    #pragma unroll
    for (int c = 0; c < 4; ++c) {
      const int col = c2 + c;
      const float A  = g2[col] / sqrtf(v2[col] + EPS);
      const float Bc = (b2[col] - m2[col]) * A + be2[col];
      f32x2 hv;
      hv[0] = fmaxf(0.f, fmaf(a2[c][0], A, Bc));
      hv[1] = fmaxf(0.f, fmaf(a2[c][1], A, Bc));
      *reinterpret_cast<f32x2*>(&h2s[col][t2]) = hv;
    }
  }
  __syncthreads();

  // layer 3 + decision + ballot.  e = (logit > 0)  [== clip(round(sigmoid))]
  if (tid < TM) {
    float logit = b3[0];
    #pragma unroll
    for (int k = 0; k < 32; ++k)
      logit = fmaf(h2s[k][tid], W3[k], logit);
    unsigned long long m = __ballot(logit > 0.f);
    if (tid == 0) masks[blockIdx.x] = m;
  }
}

// ---------------- scan: per-block expert-1 counts -> exclusive offsets ------
__global__ __launch_bounds__(512) void scan_kernel(
    const unsigned long long* __restrict__ masks,
    int* __restrict__ off1s)   // [513]: off1s[b] excl prefix, off1s[512] = n1
{
  __shared__ int s[512];
  const int t = threadIdx.x;
  const int c1 = __popcll(masks[t]);
  s[t] = c1;
  __syncthreads();
  #pragma unroll
  for (int d = 1; d < 512; d <<= 1) {
    int v = (t >= d) ? s[t - d] : 0;
    __syncthreads();
    s[t] += v;
    __syncthreads();
  }
  off1s[t] = s[t] - c1;
  if (t == 511) off1s[512] = s[511];
}

// ---------------- scatter: masks + offsets -> sorted per-expert lists -------
__global__ __launch_bounds__(256) void scatter_kernel(
    const unsigned long long* __restrict__ masks,
    const int* __restrict__ off1s,
    int* __restrict__ lists)   // [0..n0) expert0, [TOK..TOK+n1) expert1
{
  const int wave = threadIdx.x >> 6;
  const int lane = threadIdx.x & 63;
  const int b = blockIdx.x * 4 + wave;          // 128 blocks x 4 waves = 512
  const unsigned long long m = masks[b];
  const int off1 = off1s[b];
  const int off0 = b * 64 - off1;
  const int r1 = __popcll(m & ((1ull << lane) - 1ull));
  const int r0 = lane - r1;
  const int tok = b * 64 + lane;
  if ((m >> lane) & 1ull) lists[TOK + off1 + r1] = tok;
  else                    lists[off0 + r0] = tok;
}

// ---------------- expert GEMM v5: gather-GEMM, GN=144 (r16 verbatim) --------
__global__ __launch_bounds__(256) void expert_gemm_kernel(
    const unsigned short* __restrict__ xb,   // [TOK][D] bf16 bits
    const unsigned short* __restrict__ WT,   // [2][P][D] bf16 bits
    const float* __restrict__ b_exp,         // [2][P]
    const int* __restrict__ off1s,           // [513], [512] = n1
    const int* __restrict__ lists,           // [2][TOK]
    float* __restrict__ out)                 // [TOK][P]
{
  constexpr int GM = 128, GN = 144, GK = 32;
  constexpr int NT = D / GK;                       // 16 K-steps
  __shared__ __align__(16) unsigned short As[4][GM * GK];   // 4 x 8 KB
  __shared__ __align__(16) unsigned short Bs[4][GN * GK];   // 4 x 9 KB

  const int tid  = threadIdx.x;
  const int wave = tid >> 6;
  const int lane = tid & 63;

  const int n1 = off1s[512];
  const int n0 = TOK - n1;
  const int T0 = (n0 + GM - 1) >> 7;
  const int T1 = (n1 + GM - 1) >> 7;

  // XCD-affine swizzle: 1320 blocks = 8 xcd x 33 tiles x 5 ptiles
  const int wg    = blockIdx.x;
  const int xcd   = wg & 7;
  const int local = wg >> 3;                       // 0..164
  const int gt    = xcd * 33 + local / 5;          // global tile id (unique)
  const int pt    = local % 5;
  if (gt >= T0 + T1) return;
  const int e  = (gt >= T0) ? 1 : 0;
  const int ne = e ? n1 : n0;
  const int m0 = (e ? gt - T0 : gt) * GM;
  const int p0 = pt * GN;
  const int* lst = lists + e * TOK;

  const int col  = lane & 15;
  const int rg   = lane >> 4;
  const int srow = lane >> 2;                       // staging row in 16-chunk
  const int sswz = (lane & 3) ^ ((srow >> 1) & 3);  // XOR swizzle (involution)

  // ---- prologue loads (before pipeline; drained so vmcnt counts staging) --
  int aid[2];                                       // A-stage row ids
  #pragma unroll
  for (int i = 0; i < 2; ++i) {
    const int r = (wave + i * 4) * 16 + srow;
    int g = m0 + r; if (g > ne - 1) g = ne - 1;
    aid[i] = lst[g];
  }
  int eid[2][4]; unsigned evalid = 0;               // epilogue ids + valid bits
  #pragma unroll
  for (int mf = 0; mf < 2; ++mf)
    #pragma unroll
    for (int j = 0; j < 4; ++j) {
      const int g = m0 + wave * 32 + mf * 16 + rg * 4 + j;
      const int gc = (g > ne - 1) ? ne - 1 : g;
      eid[mf][j] = lst[gc];
      if (g < ne) evalid |= 1u << (mf * 4 + j);
    }
  float be[9];
  #pragma unroll
  for (int nf = 0; nf < 9; ++nf)
    be[nf] = b_exp[e * P + p0 + nf * 16 + col];
  asm volatile("s_waitcnt vmcnt(0)" ::: "memory");

  f32x4 acc[2][9];
  #pragma unroll
  for (int mf = 0; mf < 2; ++mf)
    #pragma unroll
    for (int nf = 0; nf < 9; ++nf) acc[mf][nf] = (f32x4)(0.f);

  // staging: 17 wave-ops (A: chunks wave, wave+4; B: 9 chunks, wave+i*4 i<3)
  // ops/wave: wave0=5, waves1-3=4
  auto stage = [&](int b, int kt) {
    const int k0 = kt * GK;
    #pragma unroll
    for (int i = 0; i < 2; ++i) {
      const int c = wave + i * 4;
      g2lds16(xb + (size_t)aid[i] * D + k0 + sswz * 8,
              (char*)As[b] + c * 1024);
    }
    #pragma unroll
    for (int i = 0; i < 3; ++i) {
      const int c = wave + i * 4;
      if (c < 9) {
        const int pr = c * 16 + srow;
        g2lds16(WT + ((size_t)e * P + p0 + pr) * D + k0 + sswz * 8,
                (char*)Bs[b] + c * 1024);
      }
    }
  };

  stage(0, 0);
  stage(1, 1);
  stage(2, 2);

  #pragma unroll
  for (int kt = 0; kt < NT; ++kt) {
    // wait: tile kt landed; newer tiles stay in flight (counted; exact tail)
    if (kt < NT - 2) {
      if (wave == 0) asm volatile("s_waitcnt vmcnt(10)" ::: "memory");
      else           asm volatile("s_waitcnt vmcnt(8)"  ::: "memory");
    } else if (kt == NT - 2) {
      if (wave == 0) asm volatile("s_waitcnt vmcnt(5)" ::: "memory");
      else           asm volatile("s_waitcnt vmcnt(4)" ::: "memory");
    } else {
      asm volatile("s_waitcnt vmcnt(0)" ::: "memory");
    }
    __builtin_amdgcn_s_barrier();
    __builtin_amdgcn_sched_barrier(0);

    if (kt + 3 < NT) stage((kt + 3) & 3, kt + 3);

    const int buf = kt & 3;
    bf16x8 af[2];
    #pragma unroll
    for (int mf = 0; mf < 2; ++mf) {
      const int r  = wave * 32 + mf * 16 + (lane & 15);
      const int ch = (lane >> 4) ^ ((r >> 1) & 3);
      af[mf] = *(const bf16x8*)((const char*)As[buf] + r * 64 + ch * 16);
    }
    #pragma unroll
    for (int nf = 0; nf < 9; ++nf) {
      const int pr = nf * 16 + (lane & 15);
      const int ch = (lane >> 4) ^ ((pr >> 1) & 3);
      bf16x8 bfrag = *(const bf16x8*)((const char*)Bs[buf] + pr * 64 + ch * 16);
      #pragma unroll
      for (int mf = 0; mf < 2; ++mf)
        acc[mf][nf] = __builtin_amdgcn_mfma_f32_16x16x32_bf16(
            af[mf], bfrag, acc[mf][nf], 0, 0, 0);
    }
  }

  // epilogue: scatter rows to their token ids
  #pragma unroll
  for (int nf = 0; nf < 9; ++nf) {
    const int p = p0 + nf * 16 + col;
    #pragma unroll
    for (int mf = 0; mf < 2; ++mf) {
      #pragma unroll
      for (int j = 0; j < 4; ++j) {
        if (evalid & (1u << (mf * 4 + j)))
          out[(size_t)eid[mf][j] * P + p] = acc[mf][nf][j] + be[nf];
      }
    }
  }
}

extern "C" void kernel_launch(void* const* d_in, const int* in_sizes, int n_in,
                              void* d_out, int out_size, void* d_ws, size_t ws_size,
                              hipStream_t stream) {
  const float* x     = (const float*)d_in[0];
  const float* W_exp = (const float*)d_in[1];
  const float* b_exp = (const float*)d_in[2];
  const float* W1 = (const float*)d_in[3];
  const float* b1 = (const float*)d_in[4];
  const float* g1 = (const float*)d_in[5];
  const float* be1 = (const float*)d_in[6];
  const float* m1 = (const float*)d_in[7];
  const float* v1 = (const float*)d_in[8];
  const float* W2 = (const float*)d_in[9];
  const float* b2 = (const float*)d_in[10];
  const float* g2 = (const float*)d_in[11];
  const float* be2 = (const float*)d_in[12];
  const float* m2 = (const float*)d_in[13];
  const float* v2 = (const float*)d_in[14];
  const float* W3 = (const float*)d_in[15];
  const float* b3 = (const float*)d_in[16];
  float* out = (float*)d_out;

  // ws layout: EXACTLY r8's replay-proven footprint.
  char* wsb = (char*)d_ws;
  unsigned short* xb = (unsigned short*)wsb;                       // 32 MB
  unsigned short* WT = (unsigned short*)(wsb + 33554432);          // 1.44 MB
  unsigned long long* masks = (unsigned long long*)(wsb + 35028992); // 4 KB
  int* off1s = (int*)(wsb + 35033088);                             // 2052 B
  int* lists = (int*)(wsb + 35036160);                             // 256 KB

  hipLaunchKernelGGL(wconv_kernel, dim3(D / 16, P / 16, 2), dim3(16, 16),
                     0, stream, W_exp, WT);
  hipLaunchKernelGGL(classifier_kernel, dim3(TOK / 64), dim3(256), 0, stream,
                     x, W1, b1, g1, be1, m1, v1, W2, b2, g2, be2, m2, v2, W3, b3,
                     xb, masks);
  hipLaunchKernelGGL(scan_kernel, dim3(1), dim3(512), 0, stream, masks, off1s);
  hipLaunchKernelGGL(scatter_kernel, dim3(128), dim3(256), 0, stream,
                     masks, off1s, lists);
  hipLaunchKernelGGL(expert_gemm_kernel, dim3(8 * 33 * 5), dim3(256),
                     0, stream, xb, WT, b_exp, off1s, lists, out);
}

// Round 20
// 123.182 us; speedup vs baseline: 1.6632x; 1.6632x over previous
//
#include <hip/hip_runtime.h>

#define DEV __device__ __forceinline__

typedef __bf16 bf16x8 __attribute__((ext_vector_type(8)));
typedef float f32x4 __attribute__((ext_vector_type(4)));
typedef float f32x2 __attribute__((ext_vector_type(2)));

constexpr int TOK = 32768;   // B*N tokens
constexpr int D   = 512;
constexpr int P   = 720;
constexpr float EPS = 1e-5f;

DEV unsigned short f2bf(float f) {
  unsigned u = __float_as_uint(f);
  u += 0x7FFFu + ((u >> 16) & 1u);   // RNE (normals; inputs are finite randoms)
  return (unsigned short)(u >> 16);
}

DEV void g2lds16(const void* g, void* l) {
  __builtin_amdgcn_global_load_lds(
      (__attribute__((address_space(1))) void*)g,
      (__attribute__((address_space(3))) void*)l, 16, 0, 0);
}

// ---------------- W_exp [2][D][P] fp32 -> WT [2][P][D] bf16 -----------------
__global__ void wconv_kernel(const float* __restrict__ W,
                             unsigned short* __restrict__ WT) {
  __shared__ float ls[16][17];
  const int e  = blockIdx.z;
  const int d0 = blockIdx.x * 16, p0 = blockIdx.y * 16;
  const int tx = threadIdx.x, ty = threadIdx.y;
  ls[ty][tx] = W[((size_t)e * D + d0 + ty) * P + p0 + tx];
  __syncthreads();
  WT[((size_t)e * P + p0 + ty) * D + d0 + tx] = f2bf(ls[tx][ty]);
}

// ---------------- classifier v11 (r16 verbatim): K-split-2, TM=64 -----------
__global__ __launch_bounds__(256, 3) void classifier_kernel(
    const float* __restrict__ x,
    const float* __restrict__ W1, const float* __restrict__ b1,
    const float* __restrict__ g1, const float* __restrict__ be1,
    const float* __restrict__ m1, const float* __restrict__ v1,
    const float* __restrict__ W2, const float* __restrict__ b2,
    const float* __restrict__ g2, const float* __restrict__ be2,
    const float* __restrict__ m2, const float* __restrict__ v2,
    const float* __restrict__ W3, const float* __restrict__ b3,
    unsigned short* __restrict__ xb, unsigned long long* __restrict__ masks)
{
  constexpr int TM = 64, BK = 32;
  __shared__ __align__(16) char smem[50176];
  float (*xs)[32][68]  = (float(*)[32][68])smem;
  float (*ws)[32][128] = (float(*)[32][128])(smem + 17408);
  float (*h1s)[68]     = (float(*)[68])smem;
  float (*h2s)[68]     = (float(*)[68])(smem + 34816);

  const int tid  = threadIdx.x;
  const int wave = tid >> 6;
  const int lane = tid & 63;
  const int t0   = blockIdx.x * TM;

  const int xr = tid >> 2;
  const int xc = (tid & 3) * 4;

  const int kb = (tid >> 7) * 16;   // 0 (waves 0-1) or 16 (waves 2-3)
  const int th = tid & 127;
  const int tg = th >> 4;           // tokens tg*8..+7
  const int cg = th & 15;           // cols cg*4..+3 and 64+cg*4..+3

  float acc[8][8];
  #pragma unroll
  for (int i = 0; i < 8; ++i)
    #pragma unroll
    for (int j = 0; j < 8; ++j) acc[i][j] = 0.f;

  float4 px0, px1;

  auto issue_x = [&](int kt) {
    const float* base = &x[(size_t)(t0 + xr) * D + kt * BK + xc];
    px0 = *reinterpret_cast<const float4*>(base);
    px1 = *reinterpret_cast<const float4*>(base + 16);
  };
  auto commit_x = [&](int b, int kt) {
    xs[b][xc + 0][xr] = px0.x;  xs[b][xc + 1][xr] = px0.y;
    xs[b][xc + 2][xr] = px0.z;  xs[b][xc + 3][xr] = px0.w;
    xs[b][xc + 16][xr] = px1.x; xs[b][xc + 17][xr] = px1.y;
    xs[b][xc + 18][xr] = px1.z; xs[b][xc + 19][xr] = px1.w;
    ushort4 u0, u1;
    u0.x = f2bf(px0.x); u0.y = f2bf(px0.y); u0.z = f2bf(px0.z); u0.w = f2bf(px0.w);
    u1.x = f2bf(px1.x); u1.y = f2bf(px1.y); u1.z = f2bf(px1.z); u1.w = f2bf(px1.w);
    unsigned short* xbase = &xb[(size_t)(t0 + xr) * D + kt * BK + xc];
    *reinterpret_cast<ushort4*>(xbase)      = u0;
    *reinterpret_cast<ushort4*>(xbase + 16) = u1;
  };
  auto issue_w = [&](int b, int kt) {
    char* ldsbase = (char*)&ws[b][0][0];
    const int kk = (lane >> 5);
    const int ch = (lane & 31) * 4;
    #pragma unroll
    for (int i = 0; i < 4; ++i) {
      const int op = wave * 4 + i;
      g2lds16(&W1[(size_t)(kt * BK + op * 2 + kk) * 128 + ch],
              (char*)ldsbase + op * 1024);
    }
  };

  issue_w(0, 0);
  issue_x(0);
  commit_x(0, 0);
  __syncthreads();

  int buf = 0;
  for (int kt = 0; kt < D / BK; ++kt) {
    const int nb = buf ^ 1;
    if (kt < D / BK - 1) {
      issue_w(nb, kt + 1);
      issue_x(kt + 1);
    }
    #pragma unroll 4
    for (int kk = 0; kk < 16; ++kk) {
      const int kr = kb + kk;
      const f32x4 xa  = *reinterpret_cast<const f32x4*>(&xs[buf][kr][tg * 8]);
      const f32x4 xv2 = *reinterpret_cast<const f32x4*>(&xs[buf][kr][tg * 8 + 4]);
      const f32x4 wa  = *reinterpret_cast<const f32x4*>(&ws[buf][kr][cg * 4]);
      const f32x4 wb  = *reinterpret_cast<const f32x4*>(&ws[buf][kr][64 + cg * 4]);
      const float xr8[8] = {xa[0], xa[1], xa[2], xa[3],
                            xv2[0], xv2[1], xv2[2], xv2[3]};
      const float wr8[8] = {wa[0], wa[1], wa[2], wa[3],
                            wb[0], wb[1], wb[2], wb[3]};
      #pragma unroll
      for (int i = 0; i < 8; ++i)
        #pragma unroll
        for (int j = 0; j < 8; ++j)
          acc[i][j] = fmaf(xr8[i], wr8[j], acc[i][j]);
    }
    if (kt < D / BK - 1) commit_x(nb, kt + 1);
    __syncthreads();
    buf = nb;
  }

  // K-split reduce + BN1 + ReLU -> h1s[col][tok]
  if (kb) {
    #pragma unroll
    for (int j = 0; j < 8; ++j) {
      const int col = (j < 4) ? (cg * 4 + j) : (60 + cg * 4 + j);
      float4 p0 = {acc[0][j], acc[1][j], acc[2][j], acc[3][j]};
      float4 p1 = {acc[4][j], acc[5][j], acc[6][j], acc[7][j]};
      *reinterpret_cast<float4*>(&h1s[col][tg * 8])     = p0;
      *reinterpret_cast<float4*>(&h1s[col][tg * 8 + 4]) = p1;
    }
  }
  __syncthreads();
  if (!kb) {
    #pragma unroll
    for (int j = 0; j < 8; ++j) {
      const int col = (j < 4) ? (cg * 4 + j) : (60 + cg * 4 + j);
      const float4 q0 = *reinterpret_cast<const float4*>(&h1s[col][tg * 8]);
      const float4 q1 = *reinterpret_cast<const float4*>(&h1s[col][tg * 8 + 4]);
      const float A  = g1[col] / sqrtf(v1[col] + EPS);
      const float Bc = (b1[col] - m1[col]) * A + be1[col];
      float4 h0, h1v;
      h0.x = fmaxf(0.f, fmaf(acc[0][j] + q0.x, A, Bc));
      h0.y = fmaxf(0.f, fmaf(acc[1][j] + q0.y, A, Bc));
      h0.z = fmaxf(0.f, fmaf(acc[2][j] + q0.z, A, Bc));
      h0.w = fmaxf(0.f, fmaf(acc[3][j] + q0.w, A, Bc));
      h1v.x = fmaxf(0.f, fmaf(acc[4][j] + q1.x, A, Bc));
      h1v.y = fmaxf(0.f, fmaf(acc[5][j] + q1.y, A, Bc));
      h1v.z = fmaxf(0.f, fmaf(acc[6][j] + q1.z, A, Bc));
      h1v.w = fmaxf(0.f, fmaf(acc[7][j] + q1.w, A, Bc));
      *reinterpret_cast<float4*>(&h1s[col][tg * 8])     = h0;
      *reinterpret_cast<float4*>(&h1s[col][tg * 8 + 4]) = h1v;
    }
  }
  __syncthreads();

  // layer 2: per thread 2 tokens x 4 cols
  {
    const int c2 = (tid & 7) * 4;
    const int t2 = (tid >> 3) * 2;
    f32x2 a2[4];
    #pragma unroll
    for (int c = 0; c < 4; ++c) a2[c] = (f32x2)0.f;
    #pragma unroll 8
    for (int j = 0; j < 128; ++j) {
      const f32x2 h = *reinterpret_cast<const f32x2*>(&h1s[j][t2]);
      const float4 w = *reinterpret_cast<const float4*>(&W2[j * 32 + c2]);
      const float wr[4] = {w.x, w.y, w.z, w.w};
      #pragma unroll
      for (int c = 0; c < 4; ++c) {
        f32x2 wv = {wr[c], wr[c]};
        a2[c] = __builtin_elementwise_fma(h, wv, a2[c]);
      }
    }
    #pragma unroll
    for (int c = 0; c < 4; ++c) {
      const int col = c2 + c;
      const float A  = g2[col] / sqrtf(v2[col] + EPS);
      const float Bc = (b2[col] - m2[col]) * A + be2[col];
      f32x2 hv;
      hv[0] = fmaxf(0.f, fmaf(a2[c][0], A, Bc));
      hv[1] = fmaxf(0.f, fmaf(a2[c][1], A, Bc));
      *reinterpret_cast<f32x2*>(&h2s[col][t2]) = hv;
    }
  }
  __syncthreads();

  // layer 3 + decision + ballot.  e = (logit > 0)  [== clip(round(sigmoid))]
  if (tid < TM) {
    float logit = b3[0];
    #pragma unroll
    for (int k = 0; k < 32; ++k)
      logit = fmaf(h2s[k][tid], W3[k], logit);
    unsigned long long m = __ballot(logit > 0.f);
    if (tid == 0) masks[blockIdx.x] = m;
  }
}

// ---------------- scan: per-block expert-1 counts -> exclusive offsets ------
__global__ __launch_bounds__(512) void scan_kernel(
    const unsigned long long* __restrict__ masks,
    int* __restrict__ off1s)   // [513]: off1s[b] excl prefix, off1s[512] = n1
{
  __shared__ int s[512];
  const int t = threadIdx.x;
  const int c1 = __popcll(masks[t]);
  s[t] = c1;
  __syncthreads();
  #pragma unroll
  for (int d = 1; d < 512; d <<= 1) {
    int v = (t >= d) ? s[t - d] : 0;
    __syncthreads();
    s[t] += v;
    __syncthreads();
  }
  off1s[t] = s[t] - c1;
  if (t == 511) off1s[512] = s[511];
}

// ---------------- scatter: masks + offsets -> sorted per-expert lists -------
__global__ __launch_bounds__(256) void scatter_kernel(
    const unsigned long long* __restrict__ masks,
    const int* __restrict__ off1s,
    int* __restrict__ lists)   // [0..n0) expert0, [TOK..TOK+n1) expert1
{
  const int wave = threadIdx.x >> 6;
  const int lane = threadIdx.x & 63;
  const int b = blockIdx.x * 4 + wave;          // 128 blocks x 4 waves = 512
  const unsigned long long m = masks[b];
  const int off1 = off1s[b];
  const int off0 = b * 64 - off1;
  const int r1 = __popcll(m & ((1ull << lane) - 1ull));
  const int r0 = lane - r1;
  const int tok = b * 64 + lane;
  if ((m >> lane) & 1ull) lists[TOK + off1 + r1] = tok;
  else                    lists[off0 + r0] = tok;
}

// ---------------- expert GEMM v6: GN=144, 3 buffers -> 3 blocks/CU ----------
// 51 KB LDS (3 x 17 KB) -> 3 blocks/CU = 12 waves (vs 8): more implicit
// wave-level overlap (m114). Depth-2 prefetch, exact counted vmcnt: steady
// wave0 vmcnt(5)/others vmcnt(4) (1 tile in flight), tail vmcnt(0). Buffer
// (kt+2)%3 staged at iter kt was last read at compute(kt-1), completed by all
// waves before barrier(kt) -> safe.
__global__ __launch_bounds__(256) void expert_gemm_kernel(
    const unsigned short* __restrict__ xb,   // [TOK][D] bf16 bits
    const unsigned short* __restrict__ WT,   // [2][P][D] bf16 bits
    const float* __restrict__ b_exp,         // [2][P]
    const int* __restrict__ off1s,           // [513], [512] = n1
    const int* __restrict__ lists,           // [2][TOK]
    float* __restrict__ out)                 // [TOK][P]
{
  constexpr int GM = 128, GN = 144, GK = 32;
  constexpr int NT = D / GK;                       // 16 K-steps
  __shared__ __align__(16) unsigned short As[3][GM * GK];   // 3 x 8 KB
  __shared__ __align__(16) unsigned short Bs[3][GN * GK];   // 3 x 9 KB

  const int tid  = threadIdx.x;
  const int wave = tid >> 6;
  const int lane = tid & 63;

  const int n1 = off1s[512];
  const int n0 = TOK - n1;
  const int T0 = (n0 + GM - 1) >> 7;
  const int T1 = (n1 + GM - 1) >> 7;

  // XCD-affine swizzle: 1320 blocks = 8 xcd x 33 tiles x 5 ptiles
  const int wg    = blockIdx.x;
  const int xcd   = wg & 7;
  const int local = wg >> 3;                       // 0..164
  const int gt    = xcd * 33 + local / 5;          // global tile id (unique)
  const int pt    = local % 5;
  if (gt >= T0 + T1) return;
  const int e  = (gt >= T0) ? 1 : 0;
  const int ne = e ? n1 : n0;
  const int m0 = (e ? gt - T0 : gt) * GM;
  const int p0 = pt * GN;
  const int* lst = lists + e * TOK;

  const int col  = lane & 15;
  const int rg   = lane >> 4;
  const int srow = lane >> 2;                       // staging row in 16-chunk
  const int sswz = (lane & 3) ^ ((srow >> 1) & 3);  // XOR swizzle (involution)

  // ---- prologue loads (before pipeline; drained so vmcnt counts staging) --
  int aid[2];                                       // A-stage row ids
  #pragma unroll
  for (int i = 0; i < 2; ++i) {
    const int r = (wave + i * 4) * 16 + srow;
    int g = m0 + r; if (g > ne - 1) g = ne - 1;
    aid[i] = lst[g];
  }
  int eid[2][4]; unsigned evalid = 0;               // epilogue ids + valid bits
  #pragma unroll
  for (int mf = 0; mf < 2; ++mf)
    #pragma unroll
    for (int j = 0; j < 4; ++j) {
      const int g = m0 + wave * 32 + mf * 16 + rg * 4 + j;
      const int gc = (g > ne - 1) ? ne - 1 : g;
      eid[mf][j] = lst[gc];
      if (g < ne) evalid |= 1u << (mf * 4 + j);
    }
  float be[9];
  #pragma unroll
  for (int nf = 0; nf < 9; ++nf)
    be[nf] = b_exp[e * P + p0 + nf * 16 + col];
  asm volatile("s_waitcnt vmcnt(0)" ::: "memory");

  f32x4 acc[2][9];
  #pragma unroll
  for (int mf = 0; mf < 2; ++mf)
    #pragma unroll
    for (int nf = 0; nf < 9; ++nf) acc[mf][nf] = (f32x4)(0.f);

  // staging: 17 wave-ops (A: chunks wave, wave+4; B: 9 chunks, wave+i*4 i<3)
  // ops/wave: wave0=5, waves1-3=4
  auto stage = [&](int b, int kt) {
    const int k0 = kt * GK;
    #pragma unroll
    for (int i = 0; i < 2; ++i) {
      const int c = wave + i * 4;
      g2lds16(xb + (size_t)aid[i] * D + k0 + sswz * 8,
              (char*)As[b] + c * 1024);
    }
    #pragma unroll
    for (int i = 0; i < 3; ++i) {
      const int c = wave + i * 4;
      if (c < 9) {
        const int pr = c * 16 + srow;
        g2lds16(WT + ((size_t)e * P + p0 + pr) * D + k0 + sswz * 8,
                (char*)Bs[b] + c * 1024);
      }
    }
  };

  stage(0, 0);
  stage(1, 1);

  #pragma unroll
  for (int kt = 0; kt < NT; ++kt) {
    // tile kt landed; (at most) 1 newer tile stays in flight
    if (kt < NT - 1) {
      if (wave == 0) asm volatile("s_waitcnt vmcnt(5)" ::: "memory");
      else           asm volatile("s_waitcnt vmcnt(4)" ::: "memory");
    } else {
      asm volatile("s_waitcnt vmcnt(0)" ::: "memory");
    }
    __builtin_amdgcn_s_barrier();
    __builtin_amdgcn_sched_barrier(0);

    if (kt + 2 < NT) stage((kt + 2) % 3, kt + 2);

    const int buf = kt % 3;
    bf16x8 af[2];
    #pragma unroll
    for (int mf = 0; mf < 2; ++mf) {
      const int r  = wave * 32 + mf * 16 + (lane & 15);
      const int ch = (lane >> 4) ^ ((r >> 1) & 3);
      af[mf] = *(const bf16x8*)((const char*)As[buf] + r * 64 + ch * 16);
    }
    #pragma unroll
    for (int nf = 0; nf < 9; ++nf) {
      const int pr = nf * 16 + (lane & 15);
      const int ch = (lane >> 4) ^ ((pr >> 1) & 3);
      bf16x8 bfrag = *(const bf16x8*)((const char*)Bs[buf] + pr * 64 + ch * 16);
      #pragma unroll
      for (int mf = 0; mf < 2; ++mf)
        acc[mf][nf] = __builtin_amdgcn_mfma_f32_16x16x32_bf16(
            af[mf], bfrag, acc[mf][nf], 0, 0, 0);
    }
  }

  // epilogue: scatter rows to their token ids
  #pragma unroll
  for (int nf = 0; nf < 9; ++nf) {
    const int p = p0 + nf * 16 + col;
    #pragma unroll
    for (int mf = 0; mf < 2; ++mf) {
      #pragma unroll
      for (int j = 0; j < 4; ++j) {
        if (evalid & (1u << (mf * 4 + j)))
          out[(size_t)eid[mf][j] * P + p] = acc[mf][nf][j] + be[nf];
      }
    }
  }
}

extern "C" void kernel_launch(void* const* d_in, const int* in_sizes, int n_in,
                              void* d_out, int out_size, void* d_ws, size_t ws_size,
                              hipStream_t stream) {
  const float* x     = (const float*)d_in[0];
  const float* W_exp = (const float*)d_in[1];
  const float* b_exp = (const float*)d_in[2];
  const float* W1 = (const float*)d_in[3];
  const float* b1 = (const float*)d_in[4];
  const float* g1 = (const float*)d_in[5];
  const float* be1 = (const float*)d_in[6];
  const float* m1 = (const float*)d_in[7];
  const float* v1 = (const float*)d_in[8];
  const float* W2 = (const float*)d_in[9];
  const float* b2 = (const float*)d_in[10];
  const float* g2 = (const float*)d_in[11];
  const float* be2 = (const float*)d_in[12];
  const float* m2 = (const float*)d_in[13];
  const float* v2 = (const float*)d_in[14];
  const float* W3 = (const float*)d_in[15];
  const float* b3 = (const float*)d_in[16];
  float* out = (float*)d_out;

  // ws layout: EXACTLY r8's replay-proven footprint.
  char* wsb = (char*)d_ws;
  unsigned short* xb = (unsigned short*)wsb;                       // 32 MB
  unsigned short* WT = (unsigned short*)(wsb + 33554432);          // 1.44 MB
  unsigned long long* masks = (unsigned long long*)(wsb + 35028992); // 4 KB
  int* off1s = (int*)(wsb + 35033088);                             // 2052 B
  int* lists = (int*)(wsb + 35036160);                             // 256 KB

  hipLaunchKernelGGL(wconv_kernel, dim3(D / 16, P / 16, 2), dim3(16, 16),
                     0, stream, W_exp, WT);
  hipLaunchKernelGGL(classifier_kernel, dim3(TOK / 64), dim3(256), 0, stream,
                     x, W1, b1, g1, be1, m1, v1, W2, b2, g2, be2, m2, v2, W3, b3,
                     xb, masks);
  hipLaunchKernelGGL(scan_kernel, dim3(1), dim3(512), 0, stream, masks, off1s);
  hipLaunchKernelGGL(scatter_kernel, dim3(128), dim3(256), 0, stream,
                     masks, off1s, lists);
  hipLaunchKernelGGL(expert_gemm_kernel, dim3(8 * 33 * 5), dim3(256),
                     0, stream, xb, WT, b_exp, off1s, lists, out);
}